// Round 10
// baseline (895.754 us; speedup 1.0000x reference)
//
#include <hip/hip_runtime.h>
#include <hip/hip_bf16.h>
#include <math.h>
#include <stdint.h>

#define DIMD 1024
#define HIDDEN 4096
#define NE 8
#define TOPK_ 2
#define T_TOKENS 8192
#define NROWS (T_TOKENS * TOPK_)   // 16384 assignment rows
#define BK 64
#define BM1 128                    // ffn1 tile: 128 x 256, 512 thr
#define BN1 256
#define BM2 128                    // ffn2 tile: 128 x 128, 256 thr (best measured)
#define BN2 128
#define MAXTILES (NROWS / 128 + NE) // 136
#define TGS 8                      // ffn1 tile-group for L2 blocking
#define SPLITK 4

typedef __bf16 bf16_t;
typedef __bf16 bf16x8 __attribute__((ext_vector_type(8)));
typedef float f32x4 __attribute__((ext_vector_type(4)));

// async global->LDS, 16B per lane; lds ptr must be wave-uniform
__device__ __forceinline__ void glds16(const void* g, void* l) {
    __builtin_amdgcn_global_load_lds(
        (const __attribute__((address_space(1))) unsigned int*)g,
        (__attribute__((address_space(3))) unsigned int*)l, 16, 0, 0);
}

// swizzled fragment read: LDS rows of 128B linear; 16B chunk c holds global
// chunk c^(row&7) (source pre-swizzled to match)
__device__ __forceinline__ bf16x8 ldfrag(const char* lds_, int row, int kelem) {
    int byte = row * 128 + ((kelem * 2) ^ ((row & 7) << 4));
    return *reinterpret_cast<const bf16x8*>(lds_ + byte);
}

// bijective XCD->contiguous remap (8 XCDs)
__device__ __forceinline__ int xcd_contig(int bid, int nwg) {
    int xcd = bid & 7;
    int lid = bid >> 3;
    int q = nwg >> 3, r = nwg & 7;
    int base = (xcd < r) ? xcd * (q + 1) : r * (q + 1) + (xcd - r) * q;
    return base + lid;
}

// ------ merged prologue: blocks 0..2047 = router(+x->bf16); rest = W1/W2 transpose ------
__global__ __launch_bounds__(256) void prologue_kernel(
    const float* __restrict__ x, const float* __restrict__ Wr, const float* __restrict__ br,
    const float* __restrict__ W1, const float* __restrict__ W2,
    float* __restrict__ logits, float* __restrict__ probs,
    float* __restrict__ tidx, float* __restrict__ tprob,
    int* __restrict__ cnt, bf16_t* __restrict__ Xb,
    bf16_t* __restrict__ W1T, bf16_t* __restrict__ W2T)
{
    __shared__ float tile[64][33];
    int bid0 = blockIdx.x;
    if (bid0 < T_TOKENS / 4) {
        // ---- router path ----
        int wave = threadIdx.x >> 6;
        int lane = threadIdx.x & 63;
        int t = bid0 * 4 + wave;
        const float* xr = x + (size_t)t * DIMD;
        double acc[NE];
#pragma unroll
        for (int e = 0; e < NE; ++e) acc[e] = 0.0;
        for (int i = 0; i < DIMD / 64; ++i) {
            int d = i * 64 + lane;
            double xv = (double)xr[d];
            float4 w0 = *reinterpret_cast<const float4*>(Wr + d * NE);
            float4 w1 = *reinterpret_cast<const float4*>(Wr + d * NE + 4);
            acc[0] += xv * (double)w0.x; acc[1] += xv * (double)w0.y;
            acc[2] += xv * (double)w0.z; acc[3] += xv * (double)w0.w;
            acc[4] += xv * (double)w1.x; acc[5] += xv * (double)w1.y;
            acc[6] += xv * (double)w1.z; acc[7] += xv * (double)w1.w;
        }
#pragma unroll
        for (int s = 32; s >= 1; s >>= 1) {
#pragma unroll
            for (int e = 0; e < NE; ++e) acc[e] += __shfl_xor(acc[e], s, 64);
        }
        if (lane == 0) {
            double lg[NE], mx = -1e300;
#pragma unroll
            for (int e = 0; e < NE; ++e) { lg[e] = acc[e] + (double)br[e]; mx = fmax(mx, lg[e]); }
            int i0 = 0; double l0 = -1e300;
#pragma unroll
            for (int e = 0; e < NE; ++e) { if (lg[e] > l0) { l0 = lg[e]; i0 = e; } }
            int i1 = -1; double l1 = -1e300;
#pragma unroll
            for (int e = 0; e < NE; ++e) { if (e == i0) continue; if (lg[e] > l1) { l1 = lg[e]; i1 = e; } }
            float pe[NE], s = 0.f;
#pragma unroll
            for (int e = 0; e < NE; ++e) { pe[e] = __expf((float)(lg[e] - mx)); s += pe[e]; }
            float inv = 1.f / s;
#pragma unroll
            for (int e = 0; e < NE; ++e) {
                pe[e] *= inv;
                logits[t * NE + e] = (float)lg[e];
                probs[t * NE + e] = pe[e];
            }
            tidx[t * 2 + 0] = (float)i0; tidx[t * 2 + 1] = (float)i1;
            tprob[t * 2 + 0] = pe[i0];   tprob[t * 2 + 1] = pe[i1];
            atomicAdd(&cnt[i0], 1); atomicAdd(&cnt[i1], 1);
        }
#pragma unroll
        for (int j = 0; j < 2; ++j) {
            int i = (j * 64 + lane) * 8;
            float4 a = *reinterpret_cast<const float4*>(xr + i);
            float4 b = *reinterpret_cast<const float4*>(xr + i + 4);
            bf16x8 o;
            o[0] = (bf16_t)a.x; o[1] = (bf16_t)a.y; o[2] = (bf16_t)a.z; o[3] = (bf16_t)a.w;
            o[4] = (bf16_t)b.x; o[5] = (bf16_t)b.y; o[6] = (bf16_t)b.z; o[7] = (bf16_t)b.w;
            *reinterpret_cast<bf16x8*>(Xb + (size_t)t * DIMD + i) = o;
        }
        return;
    }
    // ---- transpose path: 64(k) x 32(n) tile ----
    int bid = bid0 - T_TOKENS / 4;
    const float* in; bf16_t* out; int K, N, kt, nt, e;
    if (bid < 16384) {                 // W1: K=1024 (16 kt), N=4096 (128 nt)
        in = W1; out = W1T; K = DIMD; N = HIDDEN;
        e = bid >> 11; int rem = bid & 2047;
        kt = rem & 15; nt = rem >> 4;
    } else {                           // W2: K=4096 (64 kt), N=1024 (32 nt)
        bid -= 16384;
        in = W2; out = W2T; K = HIDDEN; N = DIMD;
        e = bid >> 11; int rem = bid & 2047;
        kt = rem & 63; nt = rem >> 6;
    }
    int k0 = kt * 64;
    int n0 = nt * 32;
    const float* ip = in + (size_t)e * K * N;
    bf16_t* op = out + (size_t)e * N * K;
    int t = threadIdx.x;
    int r = t >> 2;            // 0..63
    int c = (t & 3) * 8;       // 0,8,16,24
    float4 v0 = *reinterpret_cast<const float4*>(ip + (size_t)(k0 + r) * N + n0 + c);
    float4 v1 = *reinterpret_cast<const float4*>(ip + (size_t)(k0 + r) * N + n0 + c + 4);
    tile[r][c] = v0.x; tile[r][c + 1] = v0.y; tile[r][c + 2] = v0.z; tile[r][c + 3] = v0.w;
    tile[r][c + 4] = v1.x; tile[r][c + 5] = v1.y; tile[r][c + 6] = v1.z; tile[r][c + 7] = v1.w;
    __syncthreads();
    int nn = t >> 3;           // 0..31
    int kk = (t & 7) * 8;      // 0..56
    bf16x8 o;
#pragma unroll
    for (int j = 0; j < 8; ++j) o[j] = (bf16_t)tile[kk + j][nn];
    *reinterpret_cast<bf16x8*>(op + (size_t)(n0 + nn) * K + k0 + kk) = o;
}

// ---------------- parallel prefix + tile descriptors (BM=128) ----------------
__global__ __launch_bounds__(256) void prefix_kernel(
    const int* __restrict__ cnt, int* __restrict__ offsets,
    int* __restrict__ tileE, int* __restrict__ tileRow, int* __restrict__ numTiles)
{
    __shared__ int soff[NE + 1], scnt[NE];
    int t = threadIdx.x;
    if (t == 0) {
        int off = 0;
        for (int e = 0; e < NE; ++e) { scnt[e] = cnt[e]; soff[e] = off; off += scnt[e]; }
        soff[NE] = off;
        int nt = 0;
        for (int e = 0; e < NE; ++e) nt += (scnt[e] + 127) / 128;
        *numTiles = nt;
    }
    __syncthreads();
    if (t <= NE) offsets[t] = soff[t];
    if (t < MAXTILES) {
        int acc = 0;
#pragma unroll
        for (int e = 0; e < NE; ++e) {
            int ntE = (scnt[e] + 127) / 128;
            if (t < acc + ntE) { tileE[t] = e; tileRow[t] = soff[e] + (t - acc) * 128; return; }
            acc += ntE;
        }
    }
}

// ---------------- scatter: LDS cursors ----------------
__global__ __launch_bounds__(256) void scatter_kernel(
    const float* __restrict__ tidx, const float* __restrict__ tprob,
    const int* __restrict__ offsets, int* __restrict__ gcursor,
    int* __restrict__ rowToken, float* __restrict__ rowProb)
{
    __shared__ int lcnt[NE], lbase[NE];
    int t = blockIdx.x * 256 + threadIdx.x;
    if (threadIdx.x < NE) lcnt[threadIdx.x] = 0;
    __syncthreads();
    int e0 = (int)tidx[t * 2 + 0], e1 = (int)tidx[t * 2 + 1];
    float p0 = tprob[t * 2 + 0],   p1 = tprob[t * 2 + 1];
    int r0l = atomicAdd(&lcnt[e0], 1);
    int r1l = atomicAdd(&lcnt[e1], 1);
    __syncthreads();
    if (threadIdx.x < NE) lbase[threadIdx.x] = atomicAdd(&gcursor[threadIdx.x], lcnt[threadIdx.x]);
    __syncthreads();
    int r0 = offsets[e0] + lbase[e0] + r0l;
    int r1 = offsets[e1] + lbase[e1] + r1l;
    rowToken[r0] = t; rowProb[r0] = p0;
    rowToken[r1] = t; rowProb[r1] = p1;
}

// ---------------- pass 1: h = gelu(Xg @ W1 + b1), 128x256, 512 thr ----------------
__global__ __launch_bounds__(512) void ffn1_kernel(
    const bf16_t* __restrict__ Xb, const bf16_t* __restrict__ W1T, const float* __restrict__ b1,
    const int* __restrict__ tileE, const int* __restrict__ tileRow, const int* __restrict__ numTiles,
    const int* __restrict__ offsets, const int* __restrict__ rowToken,
    bf16_t* __restrict__ h)
{
    const int NB = HIDDEN / BN1;   // 16
    int logical = xcd_contig(blockIdx.x, gridDim.x);
    int tg  = logical / (NB * TGS);
    int rem = logical % (NB * TGS);
    int nb  = rem / TGS;
    int ti  = rem % TGS;
    int tile = tg * TGS + ti;
    if (tile >= *numTiles) return;
    int e = tileE[tile];
    int row0 = tileRow[tile];
    int rend = offsets[e + 1];
    int n0 = nb * BN1;

    __shared__ __align__(16) char lds[49152];   // A 16KB | B 32KB

    int tid = threadIdx.x;
    int lane = tid & 63;
    int wid = tid >> 6;
    int wr = (wid >> 2) * 64;   // 2M x 4N waves, 64x64 out each
    int wc = (wid & 3) * 64;
    int rr = lane & 15;
    int k4 = (lane >> 4) * 8;

    int srow = tid >> 3;                       // 0..63
    int xc = (((tid & 7) ^ (srow & 7)) << 4);  // source pre-swizzle
    const char *pa0, *pa1, *pb0, *pb1, *pb2, *pb3;
    {
        int g0 = row0 + srow;      if (g0 > NROWS - 1) g0 = NROWS - 1;
        int g1 = row0 + 64 + srow; if (g1 > NROWS - 1) g1 = NROWS - 1;
        pa0 = (const char*)(Xb + (size_t)rowToken[g0] * DIMD) + xc;
        pa1 = (const char*)(Xb + (size_t)rowToken[g1] * DIMD) + xc;
        pb0 = (const char*)(W1T + ((size_t)e * HIDDEN + n0 + srow) * DIMD) + xc;
        pb1 = (const char*)(W1T + ((size_t)e * HIDDEN + n0 + 64 + srow) * DIMD) + xc;
        pb2 = (const char*)(W1T + ((size_t)e * HIDDEN + n0 + 128 + srow) * DIMD) + xc;
        pb3 = (const char*)(W1T + ((size_t)e * HIDDEN + n0 + 192 + srow) * DIMD) + xc;
    }

    f32x4 acc[4][4];
#pragma unroll
    for (int i = 0; i < 4; ++i)
#pragma unroll
        for (int j = 0; j < 4; ++j) acc[i][j] = f32x4{0.f, 0.f, 0.f, 0.f};

    for (int t_ = 0; t_ < DIMD / BK; ++t_) {
        int kb = t_ * 128;
        glds16(pa0 + kb, lds + wid * 1024);
        glds16(pa1 + kb, lds + 8192 + wid * 1024);
        glds16(pb0 + kb, lds + 16384 + wid * 1024);
        glds16(pb1 + kb, lds + 24576 + wid * 1024);
        glds16(pb2 + kb, lds + 32768 + wid * 1024);
        glds16(pb3 + kb, lds + 40960 + wid * 1024);
        __syncthreads();
#pragma unroll
        for (int ks = 0; ks < 2; ++ks) {
            int kk = ks * 32 + k4;
            bf16x8 b_[4], a_[4];
#pragma unroll
            for (int n = 0; n < 4; ++n) b_[n] = ldfrag(lds + 16384, wc + n * 16 + rr, kk);
#pragma unroll
            for (int m = 0; m < 4; ++m) a_[m] = ldfrag(lds, wr + m * 16 + rr, kk);
#pragma unroll
            for (int m = 0; m < 4; ++m)
#pragma unroll
                for (int n = 0; n < 4; ++n)
                    acc[m][n] = __builtin_amdgcn_mfma_f32_16x16x32_bf16(a_[m], b_[n], acc[m][n], 0, 0, 0);
        }
        __syncthreads();
    }

    int crow = (lane >> 4) * 4;
    int ccol = lane & 15;
#pragma unroll
    for (int m = 0; m < 4; ++m) {
#pragma unroll
        for (int n = 0; n < 4; ++n) {
            int col = wc + n * 16 + ccol;
            float bias = b1[e * HIDDEN + n0 + col];
#pragma unroll
            for (int r = 0; r < 4; ++r) {
                int row = row0 + wr + m * 16 + crow + r;
                if (row < rend) {
                    float v = acc[m][n][r] + bias;
                    float g = 0.5f * v * (1.0f + erff(v * 0.70710678118654752f));
                    h[(size_t)row * HIDDEN + n0 + col] = (bf16_t)g;
                }
            }
        }
    }
}

// ---------------- pass 2: mixed += p * (Hg @ W2 + b2), 128x128, 256 thr, split-K ----------------
__global__ __launch_bounds__(256) void ffn2_kernel(
    const bf16_t* __restrict__ h, const bf16_t* __restrict__ W2T, const float* __restrict__ b2,
    const int* __restrict__ tileE, const int* __restrict__ tileRow, const int* __restrict__ numTiles,
    const int* __restrict__ offsets, const int* __restrict__ rowToken, const float* __restrict__ rowProb,
    float* __restrict__ mixed)
{
    const int NB = DIMD / BN2;  // 8
    int logical = xcd_contig(blockIdx.x, gridDim.x);
    int z = logical / (MAXTILES * NB);
    int rem = logical % (MAXTILES * NB);
    int tile = rem / NB;
    int nb = rem % NB;
    if (tile >= *numTiles) return;
    int e = tileE[tile];
    int row0 = tileRow[tile];
    int rend = offsets[e + 1];
    int n0 = nb * BN2;
    const int khalf = HIDDEN / SPLITK;   // 1024
    int khb = z * khalf * 2;             // byte offset of K-slice

    __shared__ __align__(16) char lds[32768];

    int tid = threadIdx.x;
    int lane = tid & 63;
    int wid = tid >> 6;
    int wr = (wid >> 1) * 64;
    int wc = (wid & 1) * 64;
    int rr = lane & 15;
    int k4 = (lane >> 4) * 8;

    int srow = tid >> 3;                       // 0..31
    int xc = (((tid & 7) ^ (srow & 7)) << 4);
    const char *pa0, *pa1, *pa2, *pa3, *pb0, *pb1, *pb2, *pb3;
    {
        int g0 = row0 + srow;      if (g0 > NROWS - 1) g0 = NROWS - 1;
        int g1 = row0 + 32 + srow; if (g1 > NROWS - 1) g1 = NROWS - 1;
        int g2 = row0 + 64 + srow; if (g2 > NROWS - 1) g2 = NROWS - 1;
        int g3 = row0 + 96 + srow; if (g3 > NROWS - 1) g3 = NROWS - 1;
        pa0 = (const char*)(h + (size_t)g0 * HIDDEN) + khb + xc;
        pa1 = (const char*)(h + (size_t)g1 * HIDDEN) + khb + xc;
        pa2 = (const char*)(h + (size_t)g2 * HIDDEN) + khb + xc;
        pa3 = (const char*)(h + (size_t)g3 * HIDDEN) + khb + xc;
        pb0 = (const char*)(W2T + ((size_t)e * DIMD + n0 + srow) * HIDDEN) + khb + xc;
        pb1 = (const char*)(W2T + ((size_t)e * DIMD + n0 + 32 + srow) * HIDDEN) + khb + xc;
        pb2 = (const char*)(W2T + ((size_t)e * DIMD + n0 + 64 + srow) * HIDDEN) + khb + xc;
        pb3 = (const char*)(W2T + ((size_t)e * DIMD + n0 + 96 + srow) * HIDDEN) + khb + xc;
    }

    f32x4 acc[4][4];
#pragma unroll
    for (int i = 0; i < 4; ++i)
#pragma unroll
        for (int j = 0; j < 4; ++j) acc[i][j] = f32x4{0.f, 0.f, 0.f, 0.f};

    for (int t_ = 0; t_ < khalf / BK; ++t_) {
        int kb = t_ * 128;
        char* dA = lds + wid * 1024;
        char* dB = lds + 16384 + wid * 1024;
        glds16(pa0 + kb, dA);          glds16(pb0 + kb, dB);
        glds16(pa1 + kb, dA + 4096);   glds16(pb1 + kb, dB + 4096);
        glds16(pa2 + kb, dA + 8192);   glds16(pb2 + kb, dB + 8192);
        glds16(pa3 + kb, dA + 12288);  glds16(pb3 + kb, dB + 12288);
        __syncthreads();
#pragma unroll
        for (int ks = 0; ks < 2; ++ks) {
            int kk = ks * 32 + k4;
            bf16x8 a_[4], b_[4];
#pragma unroll
            for (int m = 0; m < 4; ++m) a_[m] = ldfrag(lds, wr + m * 16 + rr, kk);
#pragma unroll
            for (int n = 0; n < 4; ++n) b_[n] = ldfrag(lds + 16384, wc + n * 16 + rr, kk);
#pragma unroll
            for (int m = 0; m < 4; ++m)
#pragma unroll
                for (int n = 0; n < 4; ++n)
                    acc[m][n] = __builtin_amdgcn_mfma_f32_16x16x32_bf16(a_[m], b_[n], acc[m][n], 0, 0, 0);
        }
        __syncthreads();
    }

    int crow = (lane >> 4) * 4;
    int ccol = lane & 15;
    int dobias = (z == 0);
#pragma unroll
    for (int m = 0; m < 4; ++m) {
#pragma unroll
        for (int n = 0; n < 4; ++n) {
            int col = wc + n * 16 + ccol;
            int dcol = n0 + col;
            float bias = dobias ? b2[e * DIMD + dcol] : 0.f;
#pragma unroll
            for (int r = 0; r < 4; ++r) {
                int row = row0 + wr + m * 16 + crow + r;
                if (row < rend) {
                    float v = acc[m][n][r] + bias;
                    float p = rowProb[row];
                    int tok = rowToken[row];
                    atomicAdd(&mixed[(size_t)tok * DIMD + dcol], p * v);
                }
            }
        }
    }
}

extern "C" void kernel_launch(void* const* d_in, const int* in_sizes, int n_in,
                              void* d_out, int out_size, void* d_ws, size_t ws_size,
                              hipStream_t stream)
{
    const float* x  = (const float*)d_in[0];
    const float* Wr = (const float*)d_in[1];
    const float* br = (const float*)d_in[2];
    const float* W1 = (const float*)d_in[3];
    const float* b1 = (const float*)d_in[4];
    const float* W2 = (const float*)d_in[5];
    const float* b2 = (const float*)d_in[6];

    float* out = (float*)d_out;
    float* mixed  = out;                                   // [8192][1024]
    float* logits = out + (size_t)T_TOKENS * DIMD;
    float* probs  = logits + T_TOKENS * NE;
    float* tidx   = probs + T_TOKENS * NE;
    float* tprob  = tidx + T_TOKENS * TOPK_;

    char* p = (char*)d_ws;
    auto alloc = [&](size_t bytes) { char* r = p; p += (bytes + 255) & ~255ull; return r; };
    int*    small    = (int*)alloc(2 * NE * 4);   // [cnt | gcursor]
    int*    cnt      = small;
    int*    gcursor  = small + NE;
    int*    offsets  = (int*)alloc((NE + 1) * 4);
    int*    numTiles = (int*)alloc(4);
    int*    tileE    = (int*)alloc(MAXTILES * 4);
    int*    tileRow  = (int*)alloc(MAXTILES * 4);
    int*    rowToken = (int*)alloc(NROWS * 4);
    float*  rowProb  = (float*)alloc(NROWS * 4);
    bf16_t* W1T      = (bf16_t*)alloc((size_t)NE * HIDDEN * DIMD * 2);
    bf16_t* W2T      = (bf16_t*)alloc((size_t)NE * DIMD * HIDDEN * 2);
    bf16_t* Xb       = (bf16_t*)alloc((size_t)T_TOKENS * DIMD * 2);
    bf16_t* hbuf     = (bf16_t*)alloc((size_t)NROWS * HIDDEN * 2);

    hipMemsetAsync(small, 0, 2 * NE * 4, stream);
    hipMemsetAsync(mixed, 0, (size_t)T_TOKENS * DIMD * 4, stream);

    prologue_kernel<<<T_TOKENS / 4 + 32768, 256, 0, stream>>>(
        x, Wr, br, W1, W2, logits, probs, tidx, tprob, cnt, Xb, W1T, W2T);
    prefix_kernel<<<1, 256, 0, stream>>>(cnt, offsets, tileE, tileRow, numTiles);
    scatter_kernel<<<T_TOKENS / 256, 256, 0, stream>>>(tidx, tprob, offsets, gcursor, rowToken, rowProb);

    ffn1_kernel<<<MAXTILES * (HIDDEN / BN1), 512, 0, stream>>>(
        Xb, W1T, b1, tileE, tileRow, numTiles, offsets, rowToken, hbuf);
    ffn2_kernel<<<MAXTILES * (DIMD / BN2) * SPLITK, 256, 0, stream>>>(
        hbuf, W2T, b2, tileE, tileRow, numTiles, offsets, rowToken, rowProb, mixed);
}

// Round 11
// 785.544 us; speedup vs baseline: 1.1403x; 1.1403x over previous
//
#include <hip/hip_runtime.h>
#include <hip/hip_bf16.h>
#include <math.h>
#include <stdint.h>

#define DIMD 1024
#define HIDDEN 4096
#define NE 8
#define TOPK_ 2
#define T_TOKENS 8192
#define NROWS (T_TOKENS * TOPK_)   // 16384 assignment rows
#define BK 64
#define BM1 128                    // ffn1 tile: 128 x 256, 512 thr
#define BN1 256
#define BM2 128                    // ffn2 tile: 128 x 128, 256 thr (best measured)
#define BN2 128
#define MAXTILES (NROWS / 128 + NE) // 136
#define TGS 8                      // ffn1 tile-group for L2 blocking
#define SPLITK 2

typedef __bf16 bf16_t;
typedef __bf16 bf16x8 __attribute__((ext_vector_type(8)));
typedef float f32x4 __attribute__((ext_vector_type(4)));

// async global->LDS, 16B per lane; lds ptr must be wave-uniform
__device__ __forceinline__ void glds16(const void* g, void* l) {
    __builtin_amdgcn_global_load_lds(
        (const __attribute__((address_space(1))) unsigned int*)g,
        (__attribute__((address_space(3))) unsigned int*)l, 16, 0, 0);
}

// swizzled fragment read: LDS rows of 128B linear; 16B chunk c holds global
// chunk c^(row&7) (source pre-swizzled to match)
__device__ __forceinline__ bf16x8 ldfrag(const char* lds_, int row, int kelem) {
    int byte = row * 128 + ((kelem * 2) ^ ((row & 7) << 4));
    return *reinterpret_cast<const bf16x8*>(lds_ + byte);
}

// bijective XCD->contiguous remap (8 XCDs)
__device__ __forceinline__ int xcd_contig(int bid, int nwg) {
    int xcd = bid & 7;
    int lid = bid >> 3;
    int q = nwg >> 3, r = nwg & 7;
    int base = (xcd < r) ? xcd * (q + 1) : r * (q + 1) + (xcd - r) * q;
    return base + lid;
}

// ------ merged prologue: blocks 0..2047 = router(+x->bf16); rest = W1/W2 transpose ------
__global__ __launch_bounds__(256) void prologue_kernel(
    const float* __restrict__ x, const float* __restrict__ Wr, const float* __restrict__ br,
    const float* __restrict__ W1, const float* __restrict__ W2,
    float* __restrict__ logits, float* __restrict__ probs,
    float* __restrict__ tidx, float* __restrict__ tprob,
    int* __restrict__ cnt, bf16_t* __restrict__ Xb,
    bf16_t* __restrict__ W1T, bf16_t* __restrict__ W2T)
{
    __shared__ float tile[64][33];
    int bid0 = blockIdx.x;
    if (bid0 < T_TOKENS / 4) {
        // ---- router path ----
        int wave = threadIdx.x >> 6;
        int lane = threadIdx.x & 63;
        int t = bid0 * 4 + wave;
        const float* xr = x + (size_t)t * DIMD;
        double acc[NE];
#pragma unroll
        for (int e = 0; e < NE; ++e) acc[e] = 0.0;
        for (int i = 0; i < DIMD / 64; ++i) {
            int d = i * 64 + lane;
            double xv = (double)xr[d];
            float4 w0 = *reinterpret_cast<const float4*>(Wr + d * NE);
            float4 w1 = *reinterpret_cast<const float4*>(Wr + d * NE + 4);
            acc[0] += xv * (double)w0.x; acc[1] += xv * (double)w0.y;
            acc[2] += xv * (double)w0.z; acc[3] += xv * (double)w0.w;
            acc[4] += xv * (double)w1.x; acc[5] += xv * (double)w1.y;
            acc[6] += xv * (double)w1.z; acc[7] += xv * (double)w1.w;
        }
#pragma unroll
        for (int s = 32; s >= 1; s >>= 1) {
#pragma unroll
            for (int e = 0; e < NE; ++e) acc[e] += __shfl_xor(acc[e], s, 64);
        }
        if (lane == 0) {
            double lg[NE], mx = -1e300;
#pragma unroll
            for (int e = 0; e < NE; ++e) { lg[e] = acc[e] + (double)br[e]; mx = fmax(mx, lg[e]); }
            int i0 = 0; double l0 = -1e300;
#pragma unroll
            for (int e = 0; e < NE; ++e) { if (lg[e] > l0) { l0 = lg[e]; i0 = e; } }
            int i1 = -1; double l1 = -1e300;
#pragma unroll
            for (int e = 0; e < NE; ++e) { if (e == i0) continue; if (lg[e] > l1) { l1 = lg[e]; i1 = e; } }
            float pe[NE], s = 0.f;
#pragma unroll
            for (int e = 0; e < NE; ++e) { pe[e] = __expf((float)(lg[e] - mx)); s += pe[e]; }
            float inv = 1.f / s;
#pragma unroll
            for (int e = 0; e < NE; ++e) {
                pe[e] *= inv;
                logits[t * NE + e] = (float)lg[e];
                probs[t * NE + e] = pe[e];
            }
            tidx[t * 2 + 0] = (float)i0; tidx[t * 2 + 1] = (float)i1;
            tprob[t * 2 + 0] = pe[i0];   tprob[t * 2 + 1] = pe[i1];
            atomicAdd(&cnt[i0], 1); atomicAdd(&cnt[i1], 1);
        }
#pragma unroll
        for (int j = 0; j < 2; ++j) {
            int i = (j * 64 + lane) * 8;
            float4 a = *reinterpret_cast<const float4*>(xr + i);
            float4 b = *reinterpret_cast<const float4*>(xr + i + 4);
            bf16x8 o;
            o[0] = (bf16_t)a.x; o[1] = (bf16_t)a.y; o[2] = (bf16_t)a.z; o[3] = (bf16_t)a.w;
            o[4] = (bf16_t)b.x; o[5] = (bf16_t)b.y; o[6] = (bf16_t)b.z; o[7] = (bf16_t)b.w;
            *reinterpret_cast<bf16x8*>(Xb + (size_t)t * DIMD + i) = o;
        }
        return;
    }
    // ---- transpose path: 64(k) x 32(n) tile ----
    int bid = bid0 - T_TOKENS / 4;
    const float* in; bf16_t* out; int K, N, kt, nt, e;
    if (bid < 16384) {                 // W1: K=1024 (16 kt), N=4096 (128 nt)
        in = W1; out = W1T; K = DIMD; N = HIDDEN;
        e = bid >> 11; int rem = bid & 2047;
        kt = rem & 15; nt = rem >> 4;
    } else {                           // W2: K=4096 (64 kt), N=1024 (32 nt)
        bid -= 16384;
        in = W2; out = W2T; K = HIDDEN; N = DIMD;
        e = bid >> 11; int rem = bid & 2047;
        kt = rem & 63; nt = rem >> 6;
    }
    int k0 = kt * 64;
    int n0 = nt * 32;
    const float* ip = in + (size_t)e * K * N;
    bf16_t* op = out + (size_t)e * N * K;
    int t = threadIdx.x;
    int r = t >> 2;            // 0..63
    int c = (t & 3) * 8;       // 0,8,16,24
    float4 v0 = *reinterpret_cast<const float4*>(ip + (size_t)(k0 + r) * N + n0 + c);
    float4 v1 = *reinterpret_cast<const float4*>(ip + (size_t)(k0 + r) * N + n0 + c + 4);
    tile[r][c] = v0.x; tile[r][c + 1] = v0.y; tile[r][c + 2] = v0.z; tile[r][c + 3] = v0.w;
    tile[r][c + 4] = v1.x; tile[r][c + 5] = v1.y; tile[r][c + 6] = v1.z; tile[r][c + 7] = v1.w;
    __syncthreads();
    int nn = t >> 3;           // 0..31
    int kk = (t & 7) * 8;      // 0..56
    bf16x8 o;
#pragma unroll
    for (int j = 0; j < 8; ++j) o[j] = (bf16_t)tile[kk + j][nn];
    *reinterpret_cast<bf16x8*>(op + (size_t)(n0 + nn) * K + k0 + kk) = o;
}

// ---------------- parallel prefix + tile descriptors (BM=128) ----------------
__global__ __launch_bounds__(256) void prefix_kernel(
    const int* __restrict__ cnt, int* __restrict__ offsets,
    int* __restrict__ tileE, int* __restrict__ tileRow, int* __restrict__ numTiles)
{
    __shared__ int soff[NE + 1], scnt[NE];
    int t = threadIdx.x;
    if (t == 0) {
        int off = 0;
        for (int e = 0; e < NE; ++e) { scnt[e] = cnt[e]; soff[e] = off; off += scnt[e]; }
        soff[NE] = off;
        int nt = 0;
        for (int e = 0; e < NE; ++e) nt += (scnt[e] + 127) / 128;
        *numTiles = nt;
    }
    __syncthreads();
    if (t <= NE) offsets[t] = soff[t];
    if (t < MAXTILES) {
        int acc = 0;
#pragma unroll
        for (int e = 0; e < NE; ++e) {
            int ntE = (scnt[e] + 127) / 128;
            if (t < acc + ntE) { tileE[t] = e; tileRow[t] = soff[e] + (t - acc) * 128; return; }
            acc += ntE;
        }
    }
}

// ---------------- scatter: LDS cursors ----------------
__global__ __launch_bounds__(256) void scatter_kernel(
    const float* __restrict__ tidx, const float* __restrict__ tprob,
    const int* __restrict__ offsets, int* __restrict__ gcursor,
    int* __restrict__ rowToken, float* __restrict__ rowProb)
{
    __shared__ int lcnt[NE], lbase[NE];
    int t = blockIdx.x * 256 + threadIdx.x;
    if (threadIdx.x < NE) lcnt[threadIdx.x] = 0;
    __syncthreads();
    int e0 = (int)tidx[t * 2 + 0], e1 = (int)tidx[t * 2 + 1];
    float p0 = tprob[t * 2 + 0],   p1 = tprob[t * 2 + 1];
    int r0l = atomicAdd(&lcnt[e0], 1);
    int r1l = atomicAdd(&lcnt[e1], 1);
    __syncthreads();
    if (threadIdx.x < NE) lbase[threadIdx.x] = atomicAdd(&gcursor[threadIdx.x], lcnt[threadIdx.x]);
    __syncthreads();
    int r0 = offsets[e0] + lbase[e0] + r0l;
    int r1 = offsets[e1] + lbase[e1] + r1l;
    rowToken[r0] = t; rowProb[r0] = p0;
    rowToken[r1] = t; rowProb[r1] = p1;
}

// ---------------- pass 1: h = gelu(Xg @ W1 + b1), 128x256, 512 thr ----------------
__global__ __launch_bounds__(512) void ffn1_kernel(
    const bf16_t* __restrict__ Xb, const bf16_t* __restrict__ W1T, const float* __restrict__ b1,
    const int* __restrict__ tileE, const int* __restrict__ tileRow, const int* __restrict__ numTiles,
    const int* __restrict__ offsets, const int* __restrict__ rowToken,
    bf16_t* __restrict__ h)
{
    const int NB = HIDDEN / BN1;   // 16
    int logical = xcd_contig(blockIdx.x, gridDim.x);
    int tg  = logical / (NB * TGS);
    int rem = logical % (NB * TGS);
    int nb  = rem / TGS;
    int ti  = rem % TGS;
    int tile = tg * TGS + ti;
    if (tile >= *numTiles) return;
    int e = tileE[tile];
    int row0 = tileRow[tile];
    int rend = offsets[e + 1];
    int n0 = nb * BN1;

    __shared__ __align__(16) char lds[49152];   // A 16KB | B 32KB

    int tid = threadIdx.x;
    int lane = tid & 63;
    int wid = tid >> 6;
    int wr = (wid >> 2) * 64;   // 2M x 4N waves, 64x64 out each
    int wc = (wid & 3) * 64;
    int rr = lane & 15;
    int k4 = (lane >> 4) * 8;

    int srow = tid >> 3;                       // 0..63
    int xc = (((tid & 7) ^ (srow & 7)) << 4);  // source pre-swizzle
    const char *pa0, *pa1, *pb0, *pb1, *pb2, *pb3;
    {
        int g0 = row0 + srow;      if (g0 > NROWS - 1) g0 = NROWS - 1;
        int g1 = row0 + 64 + srow; if (g1 > NROWS - 1) g1 = NROWS - 1;
        pa0 = (const char*)(Xb + (size_t)rowToken[g0] * DIMD) + xc;
        pa1 = (const char*)(Xb + (size_t)rowToken[g1] * DIMD) + xc;
        pb0 = (const char*)(W1T + ((size_t)e * HIDDEN + n0 + srow) * DIMD) + xc;
        pb1 = (const char*)(W1T + ((size_t)e * HIDDEN + n0 + 64 + srow) * DIMD) + xc;
        pb2 = (const char*)(W1T + ((size_t)e * HIDDEN + n0 + 128 + srow) * DIMD) + xc;
        pb3 = (const char*)(W1T + ((size_t)e * HIDDEN + n0 + 192 + srow) * DIMD) + xc;
    }

    f32x4 acc[4][4];
#pragma unroll
    for (int i = 0; i < 4; ++i)
#pragma unroll
        for (int j = 0; j < 4; ++j) acc[i][j] = f32x4{0.f, 0.f, 0.f, 0.f};

    for (int t_ = 0; t_ < DIMD / BK; ++t_) {
        int kb = t_ * 128;
        glds16(pa0 + kb, lds + wid * 1024);
        glds16(pa1 + kb, lds + 8192 + wid * 1024);
        glds16(pb0 + kb, lds + 16384 + wid * 1024);
        glds16(pb1 + kb, lds + 24576 + wid * 1024);
        glds16(pb2 + kb, lds + 32768 + wid * 1024);
        glds16(pb3 + kb, lds + 40960 + wid * 1024);
        __syncthreads();
#pragma unroll
        for (int ks = 0; ks < 2; ++ks) {
            int kk = ks * 32 + k4;
            bf16x8 b_[4], a_[4];
#pragma unroll
            for (int n = 0; n < 4; ++n) b_[n] = ldfrag(lds + 16384, wc + n * 16 + rr, kk);
#pragma unroll
            for (int m = 0; m < 4; ++m) a_[m] = ldfrag(lds, wr + m * 16 + rr, kk);
#pragma unroll
            for (int m = 0; m < 4; ++m)
#pragma unroll
                for (int n = 0; n < 4; ++n)
                    acc[m][n] = __builtin_amdgcn_mfma_f32_16x16x32_bf16(a_[m], b_[n], acc[m][n], 0, 0, 0);
        }
        __syncthreads();
    }

    int crow = (lane >> 4) * 4;
    int ccol = lane & 15;
#pragma unroll
    for (int m = 0; m < 4; ++m) {
#pragma unroll
        for (int n = 0; n < 4; ++n) {
            int col = wc + n * 16 + ccol;
            float bias = b1[e * HIDDEN + n0 + col];
#pragma unroll
            for (int r = 0; r < 4; ++r) {
                int row = row0 + wr + m * 16 + crow + r;
                if (row < rend) {
                    float v = acc[m][n][r] + bias;
                    float g = 0.5f * v * (1.0f + erff(v * 0.70710678118654752f));
                    h[(size_t)row * HIDDEN + n0 + col] = (bf16_t)g;
                }
            }
        }
    }
}

// ---------------- pass 2: mixed += p * (Hg @ W2 + b2), 128x128, 256 thr, split-K=2 ----------------
__global__ __launch_bounds__(256) void ffn2_kernel(
    const bf16_t* __restrict__ h, const bf16_t* __restrict__ W2T, const float* __restrict__ b2,
    const int* __restrict__ tileE, const int* __restrict__ tileRow, const int* __restrict__ numTiles,
    const int* __restrict__ offsets, const int* __restrict__ rowToken, const float* __restrict__ rowProb,
    float* __restrict__ mixed)
{
    const int NB = DIMD / BN2;  // 8
    int logical = xcd_contig(blockIdx.x, gridDim.x);
    int z = logical / (MAXTILES * NB);
    int rem = logical % (MAXTILES * NB);
    int tile = rem / NB;
    int nb = rem % NB;
    if (tile >= *numTiles) return;
    int e = tileE[tile];
    int row0 = tileRow[tile];
    int rend = offsets[e + 1];
    int n0 = nb * BN2;
    const int khalf = HIDDEN / SPLITK;   // 2048
    int khb = z * khalf * 2;             // byte offset of K-slice

    __shared__ __align__(16) char lds[32768];

    int tid = threadIdx.x;
    int lane = tid & 63;
    int wid = tid >> 6;
    int wr = (wid >> 1) * 64;
    int wc = (wid & 1) * 64;
    int rr = lane & 15;
    int k4 = (lane >> 4) * 8;

    int srow = tid >> 3;                       // 0..31
    int xc = (((tid & 7) ^ (srow & 7)) << 4);
    const char *pa0, *pa1, *pa2, *pa3, *pb0, *pb1, *pb2, *pb3;
    {
        int g0 = row0 + srow;      if (g0 > NROWS - 1) g0 = NROWS - 1;
        int g1 = row0 + 32 + srow; if (g1 > NROWS - 1) g1 = NROWS - 1;
        int g2 = row0 + 64 + srow; if (g2 > NROWS - 1) g2 = NROWS - 1;
        int g3 = row0 + 96 + srow; if (g3 > NROWS - 1) g3 = NROWS - 1;
        pa0 = (const char*)(h + (size_t)g0 * HIDDEN) + khb + xc;
        pa1 = (const char*)(h + (size_t)g1 * HIDDEN) + khb + xc;
        pa2 = (const char*)(h + (size_t)g2 * HIDDEN) + khb + xc;
        pa3 = (const char*)(h + (size_t)g3 * HIDDEN) + khb + xc;
        pb0 = (const char*)(W2T + ((size_t)e * DIMD + n0 + srow) * HIDDEN) + khb + xc;
        pb1 = (const char*)(W2T + ((size_t)e * DIMD + n0 + 32 + srow) * HIDDEN) + khb + xc;
        pb2 = (const char*)(W2T + ((size_t)e * DIMD + n0 + 64 + srow) * HIDDEN) + khb + xc;
        pb3 = (const char*)(W2T + ((size_t)e * DIMD + n0 + 96 + srow) * HIDDEN) + khb + xc;
    }

    f32x4 acc[4][4];
#pragma unroll
    for (int i = 0; i < 4; ++i)
#pragma unroll
        for (int j = 0; j < 4; ++j) acc[i][j] = f32x4{0.f, 0.f, 0.f, 0.f};

    for (int t_ = 0; t_ < khalf / BK; ++t_) {
        int kb = t_ * 128;
        char* dA = lds + wid * 1024;
        char* dB = lds + 16384 + wid * 1024;
        glds16(pa0 + kb, dA);          glds16(pb0 + kb, dB);
        glds16(pa1 + kb, dA + 4096);   glds16(pb1 + kb, dB + 4096);
        glds16(pa2 + kb, dA + 8192);   glds16(pb2 + kb, dB + 8192);
        glds16(pa3 + kb, dA + 12288);  glds16(pb3 + kb, dB + 12288);
        __syncthreads();
#pragma unroll
        for (int ks = 0; ks < 2; ++ks) {
            int kk = ks * 32 + k4;
            bf16x8 a_[4], b_[4];
#pragma unroll
            for (int m = 0; m < 4; ++m) a_[m] = ldfrag(lds, wr + m * 16 + rr, kk);
#pragma unroll
            for (int n = 0; n < 4; ++n) b_[n] = ldfrag(lds + 16384, wc + n * 16 + rr, kk);
#pragma unroll
            for (int m = 0; m < 4; ++m)
#pragma unroll
                for (int n = 0; n < 4; ++n)
                    acc[m][n] = __builtin_amdgcn_mfma_f32_16x16x32_bf16(a_[m], b_[n], acc[m][n], 0, 0, 0);
        }
        __syncthreads();
    }

    int crow = (lane >> 4) * 4;
    int ccol = lane & 15;
    int dobias = (z == 0);
#pragma unroll
    for (int m = 0; m < 4; ++m) {
#pragma unroll
        for (int n = 0; n < 4; ++n) {
            int col = wc + n * 16 + ccol;
            int dcol = n0 + col;
            float bias = dobias ? b2[e * DIMD + dcol] : 0.f;
#pragma unroll
            for (int r = 0; r < 4; ++r) {
                int row = row0 + wr + m * 16 + crow + r;
                if (row < rend) {
                    float v = acc[m][n][r] + bias;
                    float p = rowProb[row];
                    int tok = rowToken[row];
                    atomicAdd(&mixed[(size_t)tok * DIMD + dcol], p * v);
                }
            }
        }
    }
}

extern "C" void kernel_launch(void* const* d_in, const int* in_sizes, int n_in,
                              void* d_out, int out_size, void* d_ws, size_t ws_size,
                              hipStream_t stream)
{
    const float* x  = (const float*)d_in[0];
    const float* Wr = (const float*)d_in[1];
    const float* br = (const float*)d_in[2];
    const float* W1 = (const float*)d_in[3];
    const float* b1 = (const float*)d_in[4];
    const float* W2 = (const float*)d_in[5];
    const float* b2 = (const float*)d_in[6];

    float* out = (float*)d_out;
    float* mixed  = out;                                   // [8192][1024]
    float* logits = out + (size_t)T_TOKENS * DIMD;
    float* probs  = logits + T_TOKENS * NE;
    float* tidx   = probs + T_TOKENS * NE;
    float* tprob  = tidx + T_TOKENS * TOPK_;

    char* p = (char*)d_ws;
    auto alloc = [&](size_t bytes) { char* r = p; p += (bytes + 255) & ~255ull; return r; };
    int*    small    = (int*)alloc(2 * NE * 4);   // [cnt | gcursor]
    int*    cnt      = small;
    int*    gcursor  = small + NE;
    int*    offsets  = (int*)alloc((NE + 1) * 4);
    int*    numTiles = (int*)alloc(4);
    int*    tileE    = (int*)alloc(MAXTILES * 4);
    int*    tileRow  = (int*)alloc(MAXTILES * 4);
    int*    rowToken = (int*)alloc(NROWS * 4);
    float*  rowProb  = (float*)alloc(NROWS * 4);
    bf16_t* W1T      = (bf16_t*)alloc((size_t)NE * HIDDEN * DIMD * 2);
    bf16_t* W2T      = (bf16_t*)alloc((size_t)NE * DIMD * HIDDEN * 2);
    bf16_t* Xb       = (bf16_t*)alloc((size_t)T_TOKENS * DIMD * 2);
    bf16_t* hbuf     = (bf16_t*)alloc((size_t)NROWS * HIDDEN * 2);

    hipMemsetAsync(small, 0, 2 * NE * 4, stream);
    hipMemsetAsync(mixed, 0, (size_t)T_TOKENS * DIMD * 4, stream);

    prologue_kernel<<<T_TOKENS / 4 + 32768, 256, 0, stream>>>(
        x, Wr, br, W1, W2, logits, probs, tidx, tprob, cnt, Xb, W1T, W2T);
    prefix_kernel<<<1, 256, 0, stream>>>(cnt, offsets, tileE, tileRow, numTiles);
    scatter_kernel<<<T_TOKENS / 256, 256, 0, stream>>>(tidx, tprob, offsets, gcursor, rowToken, rowProb);

    ffn1_kernel<<<MAXTILES * (HIDDEN / BN1), 512, 0, stream>>>(
        Xb, W1T, b1, tileE, tileRow, numTiles, offsets, rowToken, hbuf);
    ffn2_kernel<<<MAXTILES * (DIMD / BN2) * SPLITK, 256, 0, stream>>>(
        hbuf, W2T, b2, tileE, tileRow, numTiles, offsets, rowToken, rowProb, mixed);
}

// Round 12
// 779.438 us; speedup vs baseline: 1.1492x; 1.0078x over previous
//
#include <hip/hip_runtime.h>
#include <hip/hip_bf16.h>
#include <math.h>
#include <stdint.h>

#define DIMD 1024
#define HIDDEN 4096
#define NE 8
#define TOPK_ 2
#define T_TOKENS 8192
#define NROWS (T_TOKENS * TOPK_)   // 16384 assignment rows
#define BK 64
#define BM1 128                    // ffn1 tile: 128 x 256, 512 thr
#define BN1 256
#define BM2 128                    // ffn2 tile: 128 x 128, 256 thr (best measured)
#define BN2 128
#define MAXTILES (NROWS / 128 + NE) // 136
#define TGS 8                      // ffn1 tile-group for L2 blocking
#define SPLITK 2
#define NRB (T_TOKENS / 8)         // router blocks in prologue (512 thr = 8 tokens)

typedef __bf16 bf16_t;
typedef __bf16 bf16x8 __attribute__((ext_vector_type(8)));
typedef float f32x4 __attribute__((ext_vector_type(4)));

// async global->LDS, 16B per lane; lds ptr must be wave-uniform
__device__ __forceinline__ void glds16(const void* g, void* l) {
    __builtin_amdgcn_global_load_lds(
        (const __attribute__((address_space(1))) unsigned int*)g,
        (__attribute__((address_space(3))) unsigned int*)l, 16, 0, 0);
}

// swizzled fragment read: LDS rows of 128B linear; 16B chunk c holds global
// chunk c^(row&7) (source pre-swizzled to match)
__device__ __forceinline__ bf16x8 ldfrag(const char* lds_, int row, int kelem) {
    int byte = row * 128 + ((kelem * 2) ^ ((row & 7) << 4));
    return *reinterpret_cast<const bf16x8*>(lds_ + byte);
}

// bijective XCD->contiguous remap (8 XCDs)
__device__ __forceinline__ int xcd_contig(int bid, int nwg) {
    int xcd = bid & 7;
    int lid = bid >> 3;
    int q = nwg >> 3, r = nwg & 7;
    int base = (xcd < r) ? xcd * (q + 1) : r * (q + 1) + (xcd - r) * q;
    return base + lid;
}

// ------ merged prologue: blocks 0..NRB-1 = router(+x->bf16); rest = W1/W2 transpose ------
// transpose: 128k x 128n tiles -> 512B-contiguous reads, 256B writes, nt-fastest
__global__ __launch_bounds__(512) void prologue_kernel(
    const float* __restrict__ x, const float* __restrict__ Wr, const float* __restrict__ br,
    const float* __restrict__ W1, const float* __restrict__ W2,
    float* __restrict__ logits, float* __restrict__ probs,
    float* __restrict__ tidx, float* __restrict__ tprob,
    int* __restrict__ cnt, bf16_t* __restrict__ Xb,
    bf16_t* __restrict__ W1T, bf16_t* __restrict__ W2T)
{
    __shared__ float tile[128][132];
    int bid0 = blockIdx.x;
    if (bid0 < NRB) {
        // ---- router path: 8 waves = 8 tokens ----
        int wave = threadIdx.x >> 6;
        int lane = threadIdx.x & 63;
        int t = bid0 * 8 + wave;
        const float* xr = x + (size_t)t * DIMD;
        double acc[NE];
#pragma unroll
        for (int e = 0; e < NE; ++e) acc[e] = 0.0;
        for (int i = 0; i < DIMD / 64; ++i) {
            int d = i * 64 + lane;
            double xv = (double)xr[d];
            float4 w0 = *reinterpret_cast<const float4*>(Wr + d * NE);
            float4 w1 = *reinterpret_cast<const float4*>(Wr + d * NE + 4);
            acc[0] += xv * (double)w0.x; acc[1] += xv * (double)w0.y;
            acc[2] += xv * (double)w0.z; acc[3] += xv * (double)w0.w;
            acc[4] += xv * (double)w1.x; acc[5] += xv * (double)w1.y;
            acc[6] += xv * (double)w1.z; acc[7] += xv * (double)w1.w;
        }
#pragma unroll
        for (int s = 32; s >= 1; s >>= 1) {
#pragma unroll
            for (int e = 0; e < NE; ++e) acc[e] += __shfl_xor(acc[e], s, 64);
        }
        if (lane == 0) {
            double lg[NE], mx = -1e300;
#pragma unroll
            for (int e = 0; e < NE; ++e) { lg[e] = acc[e] + (double)br[e]; mx = fmax(mx, lg[e]); }
            int i0 = 0; double l0 = -1e300;
#pragma unroll
            for (int e = 0; e < NE; ++e) { if (lg[e] > l0) { l0 = lg[e]; i0 = e; } }
            int i1 = -1; double l1 = -1e300;
#pragma unroll
            for (int e = 0; e < NE; ++e) { if (e == i0) continue; if (lg[e] > l1) { l1 = lg[e]; i1 = e; } }
            float pe[NE], s = 0.f;
#pragma unroll
            for (int e = 0; e < NE; ++e) { pe[e] = __expf((float)(lg[e] - mx)); s += pe[e]; }
            float inv = 1.f / s;
#pragma unroll
            for (int e = 0; e < NE; ++e) {
                pe[e] *= inv;
                logits[t * NE + e] = (float)lg[e];
                probs[t * NE + e] = pe[e];
            }
            tidx[t * 2 + 0] = (float)i0; tidx[t * 2 + 1] = (float)i1;
            tprob[t * 2 + 0] = pe[i0];   tprob[t * 2 + 1] = pe[i1];
            atomicAdd(&cnt[i0], 1); atomicAdd(&cnt[i1], 1);
        }
#pragma unroll
        for (int j = 0; j < 2; ++j) {
            int i = (j * 64 + lane) * 8;
            float4 a = *reinterpret_cast<const float4*>(xr + i);
            float4 b = *reinterpret_cast<const float4*>(xr + i + 4);
            bf16x8 o;
            o[0] = (bf16_t)a.x; o[1] = (bf16_t)a.y; o[2] = (bf16_t)a.z; o[3] = (bf16_t)a.w;
            o[4] = (bf16_t)b.x; o[5] = (bf16_t)b.y; o[6] = (bf16_t)b.z; o[7] = (bf16_t)b.w;
            *reinterpret_cast<bf16x8*>(Xb + (size_t)t * DIMD + i) = o;
        }
        return;
    }
    // ---- transpose path: 128(k) x 128(n) tile, nt fastest ----
    int bid = bid0 - NRB;
    const float* in; bf16_t* out; int K, N, kt, nt, e;
    if (bid < 2048) {                  // W1: K=1024 (8 kt), N=4096 (32 nt)
        in = W1; out = W1T; K = DIMD; N = HIDDEN;
        e = bid >> 8; int rem = bid & 255;
        kt = rem >> 5; nt = rem & 31;
    } else {                           // W2: K=4096 (32 kt), N=1024 (8 nt)
        bid -= 2048;
        in = W2; out = W2T; K = HIDDEN; N = DIMD;
        e = bid >> 8; int rem = bid & 255;
        kt = rem >> 3; nt = rem & 7;
    }
    int k0 = kt * 128;
    int n0 = nt * 128;
    const float* ip = in + (size_t)e * K * N + (size_t)k0 * N + n0;
    bf16_t* op = out + (size_t)e * N * K + (size_t)n0 * K + k0;
    int t = threadIdx.x;
    int r = t >> 2;            // 0..127
    int q = t & 3;             // 0..3: 128B sub-chunk of the 512B row chunk
    const float* rp = ip + (size_t)r * N + q * 32;
#pragma unroll
    for (int i = 0; i < 8; ++i) {
        float4 v = *reinterpret_cast<const float4*>(rp + i * 4);
        *reinterpret_cast<float4*>(&tile[r][q * 32 + i * 4]) = v;
    }
    __syncthreads();
    int nn = t >> 2;           // output row 0..127
    bf16_t* wp = op + (size_t)nn * K + q * 32;
#pragma unroll
    for (int i = 0; i < 4; ++i) {
        bf16x8 o;
#pragma unroll
        for (int j = 0; j < 8; ++j) o[j] = (bf16_t)tile[q * 32 + i * 8 + j][nn];
        *reinterpret_cast<bf16x8*>(wp + i * 8) = o;
    }
}

// ---------------- parallel prefix + tile descriptors (BM=128) ----------------
__global__ __launch_bounds__(256) void prefix_kernel(
    const int* __restrict__ cnt, int* __restrict__ offsets,
    int* __restrict__ tileE, int* __restrict__ tileRow, int* __restrict__ numTiles)
{
    __shared__ int soff[NE + 1], scnt[NE];
    int t = threadIdx.x;
    if (t == 0) {
        int off = 0;
        for (int e = 0; e < NE; ++e) { scnt[e] = cnt[e]; soff[e] = off; off += scnt[e]; }
        soff[NE] = off;
        int nt = 0;
        for (int e = 0; e < NE; ++e) nt += (scnt[e] + 127) / 128;
        *numTiles = nt;
    }
    __syncthreads();
    if (t <= NE) offsets[t] = soff[t];
    if (t < MAXTILES) {
        int acc = 0;
#pragma unroll
        for (int e = 0; e < NE; ++e) {
            int ntE = (scnt[e] + 127) / 128;
            if (t < acc + ntE) { tileE[t] = e; tileRow[t] = soff[e] + (t - acc) * 128; return; }
            acc += ntE;
        }
    }
}

// ---------------- scatter: LDS cursors ----------------
__global__ __launch_bounds__(256) void scatter_kernel(
    const float* __restrict__ tidx, const float* __restrict__ tprob,
    const int* __restrict__ offsets, int* __restrict__ gcursor,
    int* __restrict__ rowToken, float* __restrict__ rowProb)
{
    __shared__ int lcnt[NE], lbase[NE];
    int t = blockIdx.x * 256 + threadIdx.x;
    if (threadIdx.x < NE) lcnt[threadIdx.x] = 0;
    __syncthreads();
    int e0 = (int)tidx[t * 2 + 0], e1 = (int)tidx[t * 2 + 1];
    float p0 = tprob[t * 2 + 0],   p1 = tprob[t * 2 + 1];
    int r0l = atomicAdd(&lcnt[e0], 1);
    int r1l = atomicAdd(&lcnt[e1], 1);
    __syncthreads();
    if (threadIdx.x < NE) lbase[threadIdx.x] = atomicAdd(&gcursor[threadIdx.x], lcnt[threadIdx.x]);
    __syncthreads();
    int r0 = offsets[e0] + lbase[e0] + r0l;
    int r1 = offsets[e1] + lbase[e1] + r1l;
    rowToken[r0] = t; rowProb[r0] = p0;
    rowToken[r1] = t; rowProb[r1] = p1;
}

// ---------------- pass 1: h = gelu(Xg @ W1 + b1), 128x256, 512 thr ----------------
__global__ __launch_bounds__(512) void ffn1_kernel(
    const bf16_t* __restrict__ Xb, const bf16_t* __restrict__ W1T, const float* __restrict__ b1,
    const int* __restrict__ tileE, const int* __restrict__ tileRow, const int* __restrict__ numTiles,
    const int* __restrict__ offsets, const int* __restrict__ rowToken,
    bf16_t* __restrict__ h)
{
    const int NB = HIDDEN / BN1;   // 16
    int logical = xcd_contig(blockIdx.x, gridDim.x);
    int tg  = logical / (NB * TGS);
    int rem = logical % (NB * TGS);
    int nb  = rem / TGS;
    int ti  = rem % TGS;
    int tile = tg * TGS + ti;
    if (tile >= *numTiles) return;
    int e = tileE[tile];
    int row0 = tileRow[tile];
    int rend = offsets[e + 1];
    int n0 = nb * BN1;

    __shared__ __align__(16) char lds[49152];   // A 16KB | B 32KB

    int tid = threadIdx.x;
    int lane = tid & 63;
    int wid = tid >> 6;
    int wr = (wid >> 2) * 64;   // 2M x 4N waves, 64x64 out each
    int wc = (wid & 3) * 64;
    int rr = lane & 15;
    int k4 = (lane >> 4) * 8;

    int srow = tid >> 3;                       // 0..63
    int xc = (((tid & 7) ^ (srow & 7)) << 4);  // source pre-swizzle
    const char *pa0, *pa1, *pb0, *pb1, *pb2, *pb3;
    {
        int g0 = row0 + srow;      if (g0 > NROWS - 1) g0 = NROWS - 1;
        int g1 = row0 + 64 + srow; if (g1 > NROWS - 1) g1 = NROWS - 1;
        pa0 = (const char*)(Xb + (size_t)rowToken[g0] * DIMD) + xc;
        pa1 = (const char*)(Xb + (size_t)rowToken[g1] * DIMD) + xc;
        pb0 = (const char*)(W1T + ((size_t)e * HIDDEN + n0 + srow) * DIMD) + xc;
        pb1 = (const char*)(W1T + ((size_t)e * HIDDEN + n0 + 64 + srow) * DIMD) + xc;
        pb2 = (const char*)(W1T + ((size_t)e * HIDDEN + n0 + 128 + srow) * DIMD) + xc;
        pb3 = (const char*)(W1T + ((size_t)e * HIDDEN + n0 + 192 + srow) * DIMD) + xc;
    }

    f32x4 acc[4][4];
#pragma unroll
    for (int i = 0; i < 4; ++i)
#pragma unroll
        for (int j = 0; j < 4; ++j) acc[i][j] = f32x4{0.f, 0.f, 0.f, 0.f};

    for (int t_ = 0; t_ < DIMD / BK; ++t_) {
        int kb = t_ * 128;
        glds16(pa0 + kb, lds + wid * 1024);
        glds16(pa1 + kb, lds + 8192 + wid * 1024);
        glds16(pb0 + kb, lds + 16384 + wid * 1024);
        glds16(pb1 + kb, lds + 24576 + wid * 1024);
        glds16(pb2 + kb, lds + 32768 + wid * 1024);
        glds16(pb3 + kb, lds + 40960 + wid * 1024);
        __syncthreads();
#pragma unroll
        for (int ks = 0; ks < 2; ++ks) {
            int kk = ks * 32 + k4;
            bf16x8 b_[4], a_[4];
#pragma unroll
            for (int n = 0; n < 4; ++n) b_[n] = ldfrag(lds + 16384, wc + n * 16 + rr, kk);
#pragma unroll
            for (int m = 0; m < 4; ++m) a_[m] = ldfrag(lds, wr + m * 16 + rr, kk);
#pragma unroll
            for (int m = 0; m < 4; ++m)
#pragma unroll
                for (int n = 0; n < 4; ++n)
                    acc[m][n] = __builtin_amdgcn_mfma_f32_16x16x32_bf16(a_[m], b_[n], acc[m][n], 0, 0, 0);
        }
        __syncthreads();
    }

    int crow = (lane >> 4) * 4;
    int ccol = lane & 15;
#pragma unroll
    for (int m = 0; m < 4; ++m) {
#pragma unroll
        for (int n = 0; n < 4; ++n) {
            int col = wc + n * 16 + ccol;
            float bias = b1[e * HIDDEN + n0 + col];
#pragma unroll
            for (int r = 0; r < 4; ++r) {
                int row = row0 + wr + m * 16 + crow + r;
                if (row < rend) {
                    float v = acc[m][n][r] + bias;
                    float g = 0.5f * v * (1.0f + erff(v * 0.70710678118654752f));
                    h[(size_t)row * HIDDEN + n0 + col] = (bf16_t)g;
                }
            }
        }
    }
}

// ---------------- pass 2: mixed += p * (Hg @ W2 + b2), 128x128, 256 thr, split-K=2 ----------------
__global__ __launch_bounds__(256) void ffn2_kernel(
    const bf16_t* __restrict__ h, const bf16_t* __restrict__ W2T, const float* __restrict__ b2,
    const int* __restrict__ tileE, const int* __restrict__ tileRow, const int* __restrict__ numTiles,
    const int* __restrict__ offsets, const int* __restrict__ rowToken, const float* __restrict__ rowProb,
    float* __restrict__ mixed)
{
    const int NB = DIMD / BN2;  // 8
    int logical = xcd_contig(blockIdx.x, gridDim.x);
    int z = logical / (MAXTILES * NB);
    int rem = logical % (MAXTILES * NB);
    int tile = rem / NB;
    int nb = rem % NB;
    if (tile >= *numTiles) return;
    int e = tileE[tile];
    int row0 = tileRow[tile];
    int rend = offsets[e + 1];
    int n0 = nb * BN2;
    const int khalf = HIDDEN / SPLITK;   // 2048
    int khb = z * khalf * 2;             // byte offset of K-slice

    __shared__ __align__(16) char lds[32768];

    int tid = threadIdx.x;
    int lane = tid & 63;
    int wid = tid >> 6;
    int wr = (wid >> 1) * 64;
    int wc = (wid & 1) * 64;
    int rr = lane & 15;
    int k4 = (lane >> 4) * 8;

    int srow = tid >> 3;                       // 0..31
    int xc = (((tid & 7) ^ (srow & 7)) << 4);
    const char *pa0, *pa1, *pa2, *pa3, *pb0, *pb1, *pb2, *pb3;
    {
        int g0 = row0 + srow;      if (g0 > NROWS - 1) g0 = NROWS - 1;
        int g1 = row0 + 32 + srow; if (g1 > NROWS - 1) g1 = NROWS - 1;
        int g2 = row0 + 64 + srow; if (g2 > NROWS - 1) g2 = NROWS - 1;
        int g3 = row0 + 96 + srow; if (g3 > NROWS - 1) g3 = NROWS - 1;
        pa0 = (const char*)(h + (size_t)g0 * HIDDEN) + khb + xc;
        pa1 = (const char*)(h + (size_t)g1 * HIDDEN) + khb + xc;
        pa2 = (const char*)(h + (size_t)g2 * HIDDEN) + khb + xc;
        pa3 = (const char*)(h + (size_t)g3 * HIDDEN) + khb + xc;
        pb0 = (const char*)(W2T + ((size_t)e * DIMD + n0 + srow) * HIDDEN) + khb + xc;
        pb1 = (const char*)(W2T + ((size_t)e * DIMD + n0 + 32 + srow) * HIDDEN) + khb + xc;
        pb2 = (const char*)(W2T + ((size_t)e * DIMD + n0 + 64 + srow) * HIDDEN) + khb + xc;
        pb3 = (const char*)(W2T + ((size_t)e * DIMD + n0 + 96 + srow) * HIDDEN) + khb + xc;
    }

    f32x4 acc[4][4];
#pragma unroll
    for (int i = 0; i < 4; ++i)
#pragma unroll
        for (int j = 0; j < 4; ++j) acc[i][j] = f32x4{0.f, 0.f, 0.f, 0.f};

    for (int t_ = 0; t_ < khalf / BK; ++t_) {
        int kb = t_ * 128;
        char* dA = lds + wid * 1024;
        char* dB = lds + 16384 + wid * 1024;
        glds16(pa0 + kb, dA);          glds16(pb0 + kb, dB);
        glds16(pa1 + kb, dA + 4096);   glds16(pb1 + kb, dB + 4096);
        glds16(pa2 + kb, dA + 8192);   glds16(pb2 + kb, dB + 8192);
        glds16(pa3 + kb, dA + 12288);  glds16(pb3 + kb, dB + 12288);
        __syncthreads();
#pragma unroll
        for (int ks = 0; ks < 2; ++ks) {
            int kk = ks * 32 + k4;
            bf16x8 a_[4], b_[4];
#pragma unroll
            for (int m = 0; m < 4; ++m) a_[m] = ldfrag(lds, wr + m * 16 + rr, kk);
#pragma unroll
            for (int n = 0; n < 4; ++n) b_[n] = ldfrag(lds + 16384, wc + n * 16 + rr, kk);
#pragma unroll
            for (int m = 0; m < 4; ++m)
#pragma unroll
                for (int n = 0; n < 4; ++n)
                    acc[m][n] = __builtin_amdgcn_mfma_f32_16x16x32_bf16(a_[m], b_[n], acc[m][n], 0, 0, 0);
        }
        __syncthreads();
    }

    int crow = (lane >> 4) * 4;
    int ccol = lane & 15;
    int dobias = (z == 0);
#pragma unroll
    for (int m = 0; m < 4; ++m) {
#pragma unroll
        for (int n = 0; n < 4; ++n) {
            int col = wc + n * 16 + ccol;
            int dcol = n0 + col;
            float bias = dobias ? b2[e * DIMD + dcol] : 0.f;
#pragma unroll
            for (int r = 0; r < 4; ++r) {
                int row = row0 + wr + m * 16 + crow + r;
                if (row < rend) {
                    float v = acc[m][n][r] + bias;
                    float p = rowProb[row];
                    int tok = rowToken[row];
                    atomicAdd(&mixed[(size_t)tok * DIMD + dcol], p * v);
                }
            }
        }
    }
}

extern "C" void kernel_launch(void* const* d_in, const int* in_sizes, int n_in,
                              void* d_out, int out_size, void* d_ws, size_t ws_size,
                              hipStream_t stream)
{
    const float* x  = (const float*)d_in[0];
    const float* Wr = (const float*)d_in[1];
    const float* br = (const float*)d_in[2];
    const float* W1 = (const float*)d_in[3];
    const float* b1 = (const float*)d_in[4];
    const float* W2 = (const float*)d_in[5];
    const float* b2 = (const float*)d_in[6];

    float* out = (float*)d_out;
    float* mixed  = out;                                   // [8192][1024]
    float* logits = out + (size_t)T_TOKENS * DIMD;
    float* probs  = logits + T_TOKENS * NE;
    float* tidx   = probs + T_TOKENS * NE;
    float* tprob  = tidx + T_TOKENS * TOPK_;

    char* p = (char*)d_ws;
    auto alloc = [&](size_t bytes) { char* r = p; p += (bytes + 255) & ~255ull; return r; };
    int*    small    = (int*)alloc(2 * NE * 4);   // [cnt | gcursor]
    int*    cnt      = small;
    int*    gcursor  = small + NE;
    int*    offsets  = (int*)alloc((NE + 1) * 4);
    int*    numTiles = (int*)alloc(4);
    int*    tileE    = (int*)alloc(MAXTILES * 4);
    int*    tileRow  = (int*)alloc(MAXTILES * 4);
    int*    rowToken = (int*)alloc(NROWS * 4);
    float*  rowProb  = (float*)alloc(NROWS * 4);
    bf16_t* W1T      = (bf16_t*)alloc((size_t)NE * HIDDEN * DIMD * 2);
    bf16_t* W2T      = (bf16_t*)alloc((size_t)NE * DIMD * HIDDEN * 2);
    bf16_t* Xb       = (bf16_t*)alloc((size_t)T_TOKENS * DIMD * 2);
    bf16_t* hbuf     = (bf16_t*)alloc((size_t)NROWS * HIDDEN * 2);

    hipMemsetAsync(small, 0, 2 * NE * 4, stream);
    hipMemsetAsync(mixed, 0, (size_t)T_TOKENS * DIMD * 4, stream);

    prologue_kernel<<<NRB + 4096, 512, 0, stream>>>(
        x, Wr, br, W1, W2, logits, probs, tidx, tprob, cnt, Xb, W1T, W2T);
    prefix_kernel<<<1, 256, 0, stream>>>(cnt, offsets, tileE, tileRow, numTiles);
    scatter_kernel<<<T_TOKENS / 256, 256, 0, stream>>>(tidx, tprob, offsets, gcursor, rowToken, rowProb);

    ffn1_kernel<<<MAXTILES * (HIDDEN / BN1), 512, 0, stream>>>(
        Xb, W1T, b1, tileE, tileRow, numTiles, offsets, rowToken, hbuf);
    ffn2_kernel<<<MAXTILES * (DIMD / BN2) * SPLITK, 256, 0, stream>>>(
        hbuf, W2T, b2, tileE, tileRow, numTiles, offsets, rowToken, rowProb, mixed);
}

// Round 13
// 716.856 us; speedup vs baseline: 1.2496x; 1.0873x over previous
//
#include <hip/hip_runtime.h>
#include <hip/hip_bf16.h>
#include <math.h>
#include <stdint.h>

#define DIMD 1024
#define HIDDEN 4096
#define NE 8
#define TOPK_ 2
#define T_TOKENS 8192
#define NROWS (T_TOKENS * TOPK_)   // 16384 assignment rows
#define BK 64
#define BM1 128                    // ffn1 tile: 128 x 256, 512 thr
#define BN1 256
#define BM2 128                    // ffn2 tile: 128 x 128, 256 thr
#define BN2 128
#define MAXTILES (NROWS / 128 + NE) // 136
#define TGS 8                      // ffn1 tile-group for L2 blocking
#define NRB (T_TOKENS / 8)         // router blocks in prologue (512 thr = 8 tokens)

typedef __bf16 bf16_t;
typedef __bf16 bf16x8 __attribute__((ext_vector_type(8)));
typedef float f32x4 __attribute__((ext_vector_type(4)));

// async global->LDS, 16B per lane; lds ptr must be wave-uniform
__device__ __forceinline__ void glds16(const void* g, void* l) {
    __builtin_amdgcn_global_load_lds(
        (const __attribute__((address_space(1))) unsigned int*)g,
        (__attribute__((address_space(3))) unsigned int*)l, 16, 0, 0);
}

// swizzled fragment read: LDS rows of 128B linear; 16B chunk c holds global
// chunk c^(row&7) (source pre-swizzled to match)
__device__ __forceinline__ bf16x8 ldfrag(const char* lds_, int row, int kelem) {
    int byte = row * 128 + ((kelem * 2) ^ ((row & 7) << 4));
    return *reinterpret_cast<const bf16x8*>(lds_ + byte);
}

// bijective XCD->contiguous remap (8 XCDs)
__device__ __forceinline__ int xcd_contig(int bid, int nwg) {
    int xcd = bid & 7;
    int lid = bid >> 3;
    int q = nwg >> 3, r = nwg & 7;
    int base = (xcd < r) ? xcd * (q + 1) : r * (q + 1) + (xcd - r) * q;
    return base + lid;
}

// ------ merged prologue: blocks 0..NRB-1 = router(+x->bf16); rest = W1/W2 transpose ------
__global__ __launch_bounds__(512) void prologue_kernel(
    const float* __restrict__ x, const float* __restrict__ Wr, const float* __restrict__ br,
    const float* __restrict__ W1, const float* __restrict__ W2,
    float* __restrict__ logits, float* __restrict__ probs,
    float* __restrict__ tidx, float* __restrict__ tprob,
    int* __restrict__ cnt, bf16_t* __restrict__ Xb,
    bf16_t* __restrict__ W1T, bf16_t* __restrict__ W2T)
{
    __shared__ float tile[128][132];
    int bid0 = blockIdx.x;
    if (bid0 < NRB) {
        // ---- router path: 8 waves = 8 tokens ----
        int wave = threadIdx.x >> 6;
        int lane = threadIdx.x & 63;
        int t = bid0 * 8 + wave;
        const float* xr = x + (size_t)t * DIMD;
        double acc[NE];
#pragma unroll
        for (int e = 0; e < NE; ++e) acc[e] = 0.0;
        for (int i = 0; i < DIMD / 64; ++i) {
            int d = i * 64 + lane;
            double xv = (double)xr[d];
            float4 w0 = *reinterpret_cast<const float4*>(Wr + d * NE);
            float4 w1 = *reinterpret_cast<const float4*>(Wr + d * NE + 4);
            acc[0] += xv * (double)w0.x; acc[1] += xv * (double)w0.y;
            acc[2] += xv * (double)w0.z; acc[3] += xv * (double)w0.w;
            acc[4] += xv * (double)w1.x; acc[5] += xv * (double)w1.y;
            acc[6] += xv * (double)w1.z; acc[7] += xv * (double)w1.w;
        }
#pragma unroll
        for (int s = 32; s >= 1; s >>= 1) {
#pragma unroll
            for (int e = 0; e < NE; ++e) acc[e] += __shfl_xor(acc[e], s, 64);
        }
        if (lane == 0) {
            double lg[NE], mx = -1e300;
#pragma unroll
            for (int e = 0; e < NE; ++e) { lg[e] = acc[e] + (double)br[e]; mx = fmax(mx, lg[e]); }
            int i0 = 0; double l0 = -1e300;
#pragma unroll
            for (int e = 0; e < NE; ++e) { if (lg[e] > l0) { l0 = lg[e]; i0 = e; } }
            int i1 = -1; double l1 = -1e300;
#pragma unroll
            for (int e = 0; e < NE; ++e) { if (e == i0) continue; if (lg[e] > l1) { l1 = lg[e]; i1 = e; } }
            float pe[NE], s = 0.f;
#pragma unroll
            for (int e = 0; e < NE; ++e) { pe[e] = __expf((float)(lg[e] - mx)); s += pe[e]; }
            float inv = 1.f / s;
#pragma unroll
            for (int e = 0; e < NE; ++e) {
                pe[e] *= inv;
                logits[t * NE + e] = (float)lg[e];
                probs[t * NE + e] = pe[e];
            }
            tidx[t * 2 + 0] = (float)i0; tidx[t * 2 + 1] = (float)i1;
            tprob[t * 2 + 0] = pe[i0];   tprob[t * 2 + 1] = pe[i1];
            atomicAdd(&cnt[i0], 1); atomicAdd(&cnt[i1], 1);
        }
#pragma unroll
        for (int j = 0; j < 2; ++j) {
            int i = (j * 64 + lane) * 8;
            float4 a = *reinterpret_cast<const float4*>(xr + i);
            float4 b = *reinterpret_cast<const float4*>(xr + i + 4);
            bf16x8 o;
            o[0] = (bf16_t)a.x; o[1] = (bf16_t)a.y; o[2] = (bf16_t)a.z; o[3] = (bf16_t)a.w;
            o[4] = (bf16_t)b.x; o[5] = (bf16_t)b.y; o[6] = (bf16_t)b.z; o[7] = (bf16_t)b.w;
            *reinterpret_cast<bf16x8*>(Xb + (size_t)t * DIMD + i) = o;
        }
        return;
    }
    // ---- transpose path: 128(k) x 128(n) tile, nt fastest ----
    int bid = bid0 - NRB;
    const float* in; bf16_t* out; int K, N, kt, nt, e;
    if (bid < 2048) {                  // W1: K=1024 (8 kt), N=4096 (32 nt)
        in = W1; out = W1T; K = DIMD; N = HIDDEN;
        e = bid >> 8; int rem = bid & 255;
        kt = rem >> 5; nt = rem & 31;
    } else {                           // W2: K=4096 (32 kt), N=1024 (8 nt)
        bid -= 2048;
        in = W2; out = W2T; K = HIDDEN; N = DIMD;
        e = bid >> 8; int rem = bid & 255;
        kt = rem >> 3; nt = rem & 7;
    }
    int k0 = kt * 128;
    int n0 = nt * 128;
    const float* ip = in + (size_t)e * K * N + (size_t)k0 * N + n0;
    bf16_t* op = out + (size_t)e * N * K + (size_t)n0 * K + k0;
    int t = threadIdx.x;
    int r = t >> 2;            // 0..127
    int q = t & 3;             // 0..3: 128B sub-chunk of the 512B row chunk
    const float* rp = ip + (size_t)r * N + q * 32;
#pragma unroll
    for (int i = 0; i < 8; ++i) {
        float4 v = *reinterpret_cast<const float4*>(rp + i * 4);
        *reinterpret_cast<float4*>(&tile[r][q * 32 + i * 4]) = v;
    }
    __syncthreads();
    int nn = t >> 2;           // output row 0..127
    bf16_t* wp = op + (size_t)nn * K + q * 32;
#pragma unroll
    for (int i = 0; i < 4; ++i) {
        bf16x8 o;
#pragma unroll
        for (int j = 0; j < 8; ++j) o[j] = (bf16_t)tile[q * 32 + i * 8 + j][nn];
        *reinterpret_cast<bf16x8*>(wp + i * 8) = o;
    }
}

// ---------------- parallel prefix + tile descriptors (BM=128) ----------------
__global__ __launch_bounds__(256) void prefix_kernel(
    const int* __restrict__ cnt, int* __restrict__ offsets,
    int* __restrict__ tileE, int* __restrict__ tileRow, int* __restrict__ numTiles)
{
    __shared__ int soff[NE + 1], scnt[NE];
    int t = threadIdx.x;
    if (t == 0) {
        int off = 0;
        for (int e = 0; e < NE; ++e) { scnt[e] = cnt[e]; soff[e] = off; off += scnt[e]; }
        soff[NE] = off;
        int nt = 0;
        for (int e = 0; e < NE; ++e) nt += (scnt[e] + 127) / 128;
        *numTiles = nt;
    }
    __syncthreads();
    if (t <= NE) offsets[t] = soff[t];
    if (t < MAXTILES) {
        int acc = 0;
#pragma unroll
        for (int e = 0; e < NE; ++e) {
            int ntE = (scnt[e] + 127) / 128;
            if (t < acc + ntE) { tileE[t] = e; tileRow[t] = soff[e] + (t - acc) * 128; return; }
            acc += ntE;
        }
    }
}

// ---------------- scatter: LDS cursors; also records token->row map ----------------
__global__ __launch_bounds__(256) void scatter_kernel(
    const float* __restrict__ tidx, const float* __restrict__ tprob,
    const int* __restrict__ offsets, int* __restrict__ gcursor,
    int* __restrict__ rowToken, int* __restrict__ tokRow)
{
    __shared__ int lcnt[NE], lbase[NE];
    int t = blockIdx.x * 256 + threadIdx.x;
    if (threadIdx.x < NE) lcnt[threadIdx.x] = 0;
    __syncthreads();
    int e0 = (int)tidx[t * 2 + 0], e1 = (int)tidx[t * 2 + 1];
    int r0l = atomicAdd(&lcnt[e0], 1);
    int r1l = atomicAdd(&lcnt[e1], 1);
    __syncthreads();
    if (threadIdx.x < NE) lbase[threadIdx.x] = atomicAdd(&gcursor[threadIdx.x], lcnt[threadIdx.x]);
    __syncthreads();
    int r0 = offsets[e0] + lbase[e0] + r0l;
    int r1 = offsets[e1] + lbase[e1] + r1l;
    rowToken[r0] = t; rowToken[r1] = t;
    tokRow[t * 2 + 0] = r0; tokRow[t * 2 + 1] = r1;
}

// ---------------- pass 1: h = gelu(Xg @ W1 + b1), 128x256, 512 thr ----------------
__global__ __launch_bounds__(512) void ffn1_kernel(
    const bf16_t* __restrict__ Xb, const bf16_t* __restrict__ W1T, const float* __restrict__ b1,
    const int* __restrict__ tileE, const int* __restrict__ tileRow, const int* __restrict__ numTiles,
    const int* __restrict__ offsets, const int* __restrict__ rowToken,
    bf16_t* __restrict__ h)
{
    const int NB = HIDDEN / BN1;   // 16
    int logical = xcd_contig(blockIdx.x, gridDim.x);
    int tg  = logical / (NB * TGS);
    int rem = logical % (NB * TGS);
    int nb  = rem / TGS;
    int ti  = rem % TGS;
    int tile = tg * TGS + ti;
    if (tile >= *numTiles) return;
    int e = tileE[tile];
    int row0 = tileRow[tile];
    int rend = offsets[e + 1];
    int n0 = nb * BN1;

    __shared__ __align__(16) char lds[49152];   // A 16KB | B 32KB

    int tid = threadIdx.x;
    int lane = tid & 63;
    int wid = tid >> 6;
    int wr = (wid >> 2) * 64;   // 2M x 4N waves, 64x64 out each
    int wc = (wid & 3) * 64;
    int rr = lane & 15;
    int k4 = (lane >> 4) * 8;

    int srow = tid >> 3;                       // 0..63
    int xc = (((tid & 7) ^ (srow & 7)) << 4);  // source pre-swizzle
    const char *pa0, *pa1, *pb0, *pb1, *pb2, *pb3;
    {
        int g0 = row0 + srow;      if (g0 > NROWS - 1) g0 = NROWS - 1;
        int g1 = row0 + 64 + srow; if (g1 > NROWS - 1) g1 = NROWS - 1;
        pa0 = (const char*)(Xb + (size_t)rowToken[g0] * DIMD) + xc;
        pa1 = (const char*)(Xb + (size_t)rowToken[g1] * DIMD) + xc;
        pb0 = (const char*)(W1T + ((size_t)e * HIDDEN + n0 + srow) * DIMD) + xc;
        pb1 = (const char*)(W1T + ((size_t)e * HIDDEN + n0 + 64 + srow) * DIMD) + xc;
        pb2 = (const char*)(W1T + ((size_t)e * HIDDEN + n0 + 128 + srow) * DIMD) + xc;
        pb3 = (const char*)(W1T + ((size_t)e * HIDDEN + n0 + 192 + srow) * DIMD) + xc;
    }

    f32x4 acc[4][4];
#pragma unroll
    for (int i = 0; i < 4; ++i)
#pragma unroll
        for (int j = 0; j < 4; ++j) acc[i][j] = f32x4{0.f, 0.f, 0.f, 0.f};

    for (int t_ = 0; t_ < DIMD / BK; ++t_) {
        int kb = t_ * 128;
        glds16(pa0 + kb, lds + wid * 1024);
        glds16(pa1 + kb, lds + 8192 + wid * 1024);
        glds16(pb0 + kb, lds + 16384 + wid * 1024);
        glds16(pb1 + kb, lds + 24576 + wid * 1024);
        glds16(pb2 + kb, lds + 32768 + wid * 1024);
        glds16(pb3 + kb, lds + 40960 + wid * 1024);
        __syncthreads();
#pragma unroll
        for (int ks = 0; ks < 2; ++ks) {
            int kk = ks * 32 + k4;
            bf16x8 b_[4], a_[4];
#pragma unroll
            for (int n = 0; n < 4; ++n) b_[n] = ldfrag(lds + 16384, wc + n * 16 + rr, kk);
#pragma unroll
            for (int m = 0; m < 4; ++m) a_[m] = ldfrag(lds, wr + m * 16 + rr, kk);
#pragma unroll
            for (int m = 0; m < 4; ++m)
#pragma unroll
                for (int n = 0; n < 4; ++n)
                    acc[m][n] = __builtin_amdgcn_mfma_f32_16x16x32_bf16(a_[m], b_[n], acc[m][n], 0, 0, 0);
        }
        __syncthreads();
    }

    int crow = (lane >> 4) * 4;
    int ccol = lane & 15;
#pragma unroll
    for (int m = 0; m < 4; ++m) {
#pragma unroll
        for (int n = 0; n < 4; ++n) {
            int col = wc + n * 16 + ccol;
            float bias = b1[e * HIDDEN + n0 + col];
#pragma unroll
            for (int r = 0; r < 4; ++r) {
                int row = row0 + wr + m * 16 + crow + r;
                if (row < rend) {
                    float v = acc[m][n][r] + bias;
                    float g = 0.5f * v * (1.0f + erff(v * 0.70710678118654752f));
                    h[(size_t)row * HIDDEN + n0 + col] = (bf16_t)g;
                }
            }
        }
    }
}

// ---------------- pass 2: part[row] = Hg @ W2 + b2 (no atomics, no split-K) ----------------
__global__ __launch_bounds__(256) void ffn2_kernel(
    const bf16_t* __restrict__ h, const bf16_t* __restrict__ W2T, const float* __restrict__ b2,
    const int* __restrict__ tileE, const int* __restrict__ tileRow, const int* __restrict__ numTiles,
    const int* __restrict__ offsets, float* __restrict__ part)
{
    const int NB = DIMD / BN2;  // 8
    int logical = xcd_contig(blockIdx.x, gridDim.x);
    int tile = logical / NB;
    int nb = logical % NB;
    if (tile >= *numTiles) return;
    int e = tileE[tile];
    int row0 = tileRow[tile];
    int rend = offsets[e + 1];
    int n0 = nb * BN2;

    __shared__ __align__(16) char lds[32768];

    int tid = threadIdx.x;
    int lane = tid & 63;
    int wid = tid >> 6;
    int wr = (wid >> 1) * 64;
    int wc = (wid & 1) * 64;
    int rr = lane & 15;
    int k4 = (lane >> 4) * 8;

    int srow = tid >> 3;                       // 0..31
    int xc = (((tid & 7) ^ (srow & 7)) << 4);
    const char *pa0, *pa1, *pa2, *pa3, *pb0, *pb1, *pb2, *pb3;
    {
        int g0 = row0 + srow;      if (g0 > NROWS - 1) g0 = NROWS - 1;
        int g1 = row0 + 32 + srow; if (g1 > NROWS - 1) g1 = NROWS - 1;
        int g2 = row0 + 64 + srow; if (g2 > NROWS - 1) g2 = NROWS - 1;
        int g3 = row0 + 96 + srow; if (g3 > NROWS - 1) g3 = NROWS - 1;
        pa0 = (const char*)(h + (size_t)g0 * HIDDEN) + xc;
        pa1 = (const char*)(h + (size_t)g1 * HIDDEN) + xc;
        pa2 = (const char*)(h + (size_t)g2 * HIDDEN) + xc;
        pa3 = (const char*)(h + (size_t)g3 * HIDDEN) + xc;
        pb0 = (const char*)(W2T + ((size_t)e * DIMD + n0 + srow) * HIDDEN) + xc;
        pb1 = (const char*)(W2T + ((size_t)e * DIMD + n0 + 32 + srow) * HIDDEN) + xc;
        pb2 = (const char*)(W2T + ((size_t)e * DIMD + n0 + 64 + srow) * HIDDEN) + xc;
        pb3 = (const char*)(W2T + ((size_t)e * DIMD + n0 + 96 + srow) * HIDDEN) + xc;
    }

    f32x4 acc[4][4];
#pragma unroll
    for (int i = 0; i < 4; ++i)
#pragma unroll
        for (int j = 0; j < 4; ++j) acc[i][j] = f32x4{0.f, 0.f, 0.f, 0.f};

    for (int t_ = 0; t_ < HIDDEN / BK; ++t_) {
        int kb = t_ * 128;
        char* dA = lds + wid * 1024;
        char* dB = lds + 16384 + wid * 1024;
        glds16(pa0 + kb, dA);          glds16(pb0 + kb, dB);
        glds16(pa1 + kb, dA + 4096);   glds16(pb1 + kb, dB + 4096);
        glds16(pa2 + kb, dA + 8192);   glds16(pb2 + kb, dB + 8192);
        glds16(pa3 + kb, dA + 12288);  glds16(pb3 + kb, dB + 12288);
        __syncthreads();
#pragma unroll
        for (int ks = 0; ks < 2; ++ks) {
            int kk = ks * 32 + k4;
            bf16x8 a_[4], b_[4];
#pragma unroll
            for (int m = 0; m < 4; ++m) a_[m] = ldfrag(lds, wr + m * 16 + rr, kk);
#pragma unroll
            for (int n = 0; n < 4; ++n) b_[n] = ldfrag(lds + 16384, wc + n * 16 + rr, kk);
#pragma unroll
            for (int m = 0; m < 4; ++m)
#pragma unroll
                for (int n = 0; n < 4; ++n)
                    acc[m][n] = __builtin_amdgcn_mfma_f32_16x16x32_bf16(a_[m], b_[n], acc[m][n], 0, 0, 0);
        }
        __syncthreads();
    }

    int crow = (lane >> 4) * 4;
    int ccol = lane & 15;
#pragma unroll
    for (int m = 0; m < 4; ++m) {
#pragma unroll
        for (int n = 0; n < 4; ++n) {
            int col = wc + n * 16 + ccol;
            int dcol = n0 + col;
            float bias = b2[e * DIMD + dcol];
#pragma unroll
            for (int r = 0; r < 4; ++r) {
                int row = row0 + wr + m * 16 + crow + r;
                if (row < rend) {
                    part[(size_t)row * DIMD + dcol] = acc[m][n][r] + bias;
                }
            }
        }
    }
}

// ---------------- reduce: mixed[tok] = p0*part[r0] + p1*part[r1] ----------------
__global__ __launch_bounds__(256) void reduce_kernel(
    const float* __restrict__ part, const float* __restrict__ tprob,
    const int* __restrict__ tokRow, float* __restrict__ mixed)
{
    int idx = blockIdx.x * 256 + threadIdx.x;   // one float4 per thread
    int tok = idx >> 8;                         // 256 quads per token
    int q = (idx & 255) * 4;
    int r0 = tokRow[tok * 2 + 0], r1 = tokRow[tok * 2 + 1];
    float p0 = tprob[tok * 2 + 0], p1 = tprob[tok * 2 + 1];
    float4 a = *reinterpret_cast<const float4*>(part + (size_t)r0 * DIMD + q);
    float4 b = *reinterpret_cast<const float4*>(part + (size_t)r1 * DIMD + q);
    float4 o;
    o.x = p0 * a.x + p1 * b.x;
    o.y = p0 * a.y + p1 * b.y;
    o.z = p0 * a.z + p1 * b.z;
    o.w = p0 * a.w + p1 * b.w;
    *reinterpret_cast<float4*>(mixed + (size_t)tok * DIMD + q) = o;
}

extern "C" void kernel_launch(void* const* d_in, const int* in_sizes, int n_in,
                              void* d_out, int out_size, void* d_ws, size_t ws_size,
                              hipStream_t stream)
{
    const float* x  = (const float*)d_in[0];
    const float* Wr = (const float*)d_in[1];
    const float* br = (const float*)d_in[2];
    const float* W1 = (const float*)d_in[3];
    const float* b1 = (const float*)d_in[4];
    const float* W2 = (const float*)d_in[5];
    const float* b2 = (const float*)d_in[6];

    float* out = (float*)d_out;
    float* mixed  = out;                                   // [8192][1024]
    float* logits = out + (size_t)T_TOKENS * DIMD;
    float* probs  = logits + T_TOKENS * NE;
    float* tidx   = probs + T_TOKENS * NE;
    float* tprob  = tidx + T_TOKENS * TOPK_;

    char* p = (char*)d_ws;
    auto alloc = [&](size_t bytes) { char* r = p; p += (bytes + 255) & ~255ull; return r; };
    int*    small    = (int*)alloc(2 * NE * 4);   // [cnt | gcursor]
    int*    cnt      = small;
    int*    gcursor  = small + NE;
    int*    offsets  = (int*)alloc((NE + 1) * 4);
    int*    numTiles = (int*)alloc(4);
    int*    tileE    = (int*)alloc(MAXTILES * 4);
    int*    tileRow  = (int*)alloc(MAXTILES * 4);
    int*    rowToken = (int*)alloc(NROWS * 4);
    int*    tokRow   = (int*)alloc(NROWS * 4);
    bf16_t* W1T      = (bf16_t*)alloc((size_t)NE * HIDDEN * DIMD * 2);
    bf16_t* W2T      = (bf16_t*)alloc((size_t)NE * DIMD * HIDDEN * 2);
    bf16_t* Xb       = (bf16_t*)alloc((size_t)T_TOKENS * DIMD * 2);
    bf16_t* hbuf     = (bf16_t*)alloc((size_t)NROWS * HIDDEN * 2);
    float*  part     = (float*)alloc((size_t)NROWS * DIMD * 4);

    hipMemsetAsync(small, 0, 2 * NE * 4, stream);

    prologue_kernel<<<NRB + 4096, 512, 0, stream>>>(
        x, Wr, br, W1, W2, logits, probs, tidx, tprob, cnt, Xb, W1T, W2T);
    prefix_kernel<<<1, 256, 0, stream>>>(cnt, offsets, tileE, tileRow, numTiles);
    scatter_kernel<<<T_TOKENS / 256, 256, 0, stream>>>(tidx, tprob, offsets, gcursor, rowToken, tokRow);

    ffn1_kernel<<<MAXTILES * (HIDDEN / BN1), 512, 0, stream>>>(
        Xb, W1T, b1, tileE, tileRow, numTiles, offsets, rowToken, hbuf);
    ffn2_kernel<<<MAXTILES * (DIMD / BN2), 256, 0, stream>>>(
        hbuf, W2T, b2, tileE, tileRow, numTiles, offsets, part);
    reduce_kernel<<<T_TOKENS * DIMD / 4 / 256, 256, 0, stream>>>(part, tprob, tokRow, mixed);
}